// Round 3
// baseline (251.084 us; speedup 1.0000x reference)
//
#include <hip/hip_runtime.h>
#include <math.h>

#define S1C 10
#define S2C 25
#define DC 128
#define NSAMP 261
#define NBATCH 2048
#define FEA_SZ (128*2048)

// ws layout (floats):
//   [0:128)    a1 = V1h1a^T w1[:128]
//   [128:256)  a2 = V1h1a^T w1[128:]
//   [256:384)  b1 = V1h0a^T w0[:128]
//   [384:512)  b2 = V1h0a^T w0[128:]
//   [512:512+16384)        W1V = Whops[:,:128] @ V1h1   (row-major [128][128])
//   [512+16384:512+32768)  W2V = Whops[:,128:] @ V1h1   (row-major [128][128])
//   [512+32768 ...)        aggF[b][s][n]  (2048*10*128)
#define WS_WV   512
#define WS_AGGF (512 + 2*128*128)

__device__ __forceinline__ float lrelu(float v) { return v > 0.f ? v : 0.01f * v; }
__device__ __forceinline__ float sigm(float v) { return 1.f / (1.f + __expf(-v)); }

__global__ void prep_kernel(const float* __restrict__ Vh1a, const float* __restrict__ w1,
                            const float* __restrict__ Vh0a, const float* __restrict__ w0,
                            float* __restrict__ ws) {
    int tid = threadIdx.x;
    for (int o = tid; o < 512; o += 256) {
        int which = o >> 7, n = o & 127;
        const float* V = (which < 2) ? Vh1a : Vh0a;
        const float* w = (which < 2) ? w1 : w0;
        int off = (which & 1) * 128;
        float acc = 0.f;
        for (int l = 0; l < 128; ++l) acc += V[l * 128 + n] * w[off + l];
        ws[o] = acc;
    }
}

__global__ void prepWV_kernel(const float* __restrict__ V1h1,
                              const float* __restrict__ Whops,
                              float* __restrict__ ws) {
    int h = threadIdx.x >> 7, n = threadIdx.x & 127;
    int task = blockIdx.x * 2 + h;          // 0..255
    int which = task >> 7, d = task & 127;  // 0 -> W1V, 1 -> W2V
    const float* Wrow = Whops + (size_t)d * 256 + which * 128;
    float acc = 0.f;
    for (int j = 0; j < 128; ++j) acc += Wrow[j] * V1h1[(size_t)j * 128 + n];
    ws[WS_WV + (size_t)task * 128 + n] = acc;
}

// One block per (b,s): grid = dim3(10, 2048).
__global__ __launch_bounds__(256) void nbr_kernel(
    const float* __restrict__ x, const int* __restrict__ samples,
    const float* __restrict__ ws, float* __restrict__ aggF,
    float* __restrict__ out)
{
    const int s = blockIdx.x, b = blockIdx.y;
    const int tid = threadIdx.x, g = tid >> 5, lane = tid & 31;

    __shared__ __align__(16) float sNbr[25][132];
    __shared__ float sD[26];
    __shared__ float sBeta[25];

    float4 a1v = *(const float4*)(ws + lane * 4);
    float4 a2v = *(const float4*)(ws + 128 + lane * 4);
    const int* sidx = samples + (size_t)b * NSAMP;

    for (int round = 0; round < 4; ++round) {
        int r = round * 8 + g;          // rows 0..24: neighbors; row 25: fea_t1[s]
        float p = 0.f;
        if (r < 26) {
            int node = (r < 25) ? sidx[11 + s * S2C + r] : sidx[1 + s];
            float4 v = *(const float4*)(x + (size_t)node * DC + lane * 4);
            if (r < 25) *(float4*)(&sNbr[r][lane * 4]) = v;
            float4 av = (r < 25) ? a2v : a1v;
            p = v.x * av.x + v.y * av.y + v.z * av.z + v.w * av.w;
        }
        for (int o = 16; o > 0; o >>= 1) p += __shfl_xor(p, o, 32);
        if (r < 26 && lane == 0) sD[r] = p;
    }
    __syncthreads();

    if (tid < 32) {
        float c1 = sD[25];
        float v = (lane < 25) ? lrelu(c1 + sD[lane]) : -3.4e38f;
        float m = v;
        for (int o = 16; o > 0; o >>= 1) m = fmaxf(m, __shfl_xor(m, o, 32));
        float e = (lane < 25) ? __expf(v - m) : 0.f;
        float ssum = e;
        for (int o = 16; o > 0; o >>= 1) ssum += __shfl_xor(ssum, o, 32);
        if (lane < 25) {
            float bt = e / ssum;
            sBeta[lane] = bt;
            out[FEA_SZ + (size_t)b * 260 + s * 26 + 1 + lane] = bt;
        }
    }
    __syncthreads();

    if (tid < 128) {
        float acc = 0.f;
        #pragma unroll
        for (int t = 0; t < 25; ++t) acc += sBeta[t] * sNbr[t][tid];
        aggF[((size_t)b * 10 + s) * 128 + tid] = acc;
    }
}

// hop GEMM core: NT tasks, activations via wave-uniform (scalar-loadable) reads.
template<int NT>
__device__ __forceinline__ void hop_gemm(const float* __restrict__ xp[NT],
                                         const float* __restrict__ ap[NT],
                                         const float* __restrict__ W1r,
                                         const float* __restrict__ W2r,
                                         float acc[NT]) {
    for (int k = 0; k < 32; ++k) {
        float4 wa = *(const float4*)(W1r + k * 4);
        float4 wb = *(const float4*)(W2r + k * 4);
        #pragma unroll
        for (int t = 0; t < NT; ++t) {
            float4 tv = *(const float4*)(xp[t] + k * 4);
            float4 av = *(const float4*)(ap[t] + k * 4);
            acc[t] += wa.x * tv.x + wa.y * tv.y + wa.z * tv.z + wa.w * tv.w
                    + wb.x * av.x + wb.y * av.y + wb.z * av.z + wb.w * av.w;
        }
    }
}

// One block per b.  hop1[s] = sigm(W1V.t1[s] + W2V.aggF[s]),
// hop0 = sigm(W1V.t0 + W2V.tbar), tbar = sum_s beta0[s] t1[s].
__global__ __launch_bounds__(256) void head_kernel(
    const float* __restrict__ x, const int* __restrict__ samples,
    const float* __restrict__ V1h0, const float* __restrict__ ws,
    const float* __restrict__ aggF, float* __restrict__ out)
{
    const int b = blockIdx.x;
    const int tid = threadIdx.x, g = tid >> 5, lane = tid & 31;
    const int d = tid & 127, h = tid >> 7;
    const float* WV = ws + WS_WV;

    __shared__ __align__(16) float sT0[128];
    __shared__ __align__(16) float sT1[10][128];
    __shared__ __align__(16) float sTbar[128];
    __shared__ __align__(16) float sHop1[10][128];
    __shared__ __align__(16) float sHop0[128];
    __shared__ __align__(16) float sHopH[128];
    __shared__ float sD1[10], sC0, sBeta0[10], sLog[12], sBetaH[10];
    __shared__ int sIdx[16];

    if (tid < 11) sIdx[tid] = samples[(size_t)b * NSAMP + tid];
    __syncthreads();

    // ---- stage t1 rows (r<10) + t0 (r=10) into LDS, fused a1/a2 dots ----
    for (int round = 0; round < 2; ++round) {
        int r = round * 8 + g;
        float p1 = 0.f, p2 = 0.f;
        if (r < 11) {
            int node = (r < 10) ? sIdx[1 + r] : sIdx[0];
            float4 v = *(const float4*)(x + (size_t)node * DC + lane * 4);
            float4 a1v = *(const float4*)(ws + lane * 4);
            float4 a2v = *(const float4*)(ws + 128 + lane * 4);
            float* dst = (r < 10) ? &sT1[r][0] : &sT0[0];
            *(float4*)(dst + lane * 4) = v;
            p1 = v.x * a1v.x + v.y * a1v.y + v.z * a1v.z + v.w * a1v.w;
            p2 = v.x * a2v.x + v.y * a2v.y + v.z * a2v.z + v.w * a2v.w;
        }
        for (int o = 16; o > 0; o >>= 1) { p1 += __shfl_xor(p1, o, 32); p2 += __shfl_xor(p2, o, 32); }
        if (r < 11 && lane == 0) { if (r < 10) sD1[r] = p2; else sC0 = p1; }
    }
    __syncthreads();

    // ---- beta0 = softmax_s(lrelu(c0 + d1[s])) ----
    if (tid < 16) {
        float v = (tid < 10) ? lrelu(sC0 + sD1[tid]) : -3.4e38f;
        float m = v;
        for (int o = 8; o > 0; o >>= 1) m = fmaxf(m, __shfl_xor(m, o, 16));
        float e = (tid < 10) ? __expf(v - m) : 0.f;
        float ssum = e;
        for (int o = 8; o > 0; o >>= 1) ssum += __shfl_xor(ssum, o, 16);
        if (tid < 10) sBeta0[tid] = e / ssum;
    }
    __syncthreads();

    // ---- tbar[n] = sum_s beta0[s] t1[s][n] ----
    if (tid < 128) {
        float acc = 0.f;
        #pragma unroll
        for (int s = 0; s < 10; ++s) acc += sBeta0[s] * sT1[s][tid];
        sTbar[tid] = acc;
    }
    __syncthreads();

    // ---- hop GEMM: each thread one d, 5 s-tasks (h picks the half).
    //      Activation reads are wave-uniform from read-only x/aggF -> scalar loads.
    {
        const float* W1r = WV + (size_t)d * 128;
        const float* W2r = WV + (size_t)(128 + d) * 128;
        const float* xp[5];
        const float* ap[5];
        const int* sidx = samples + (size_t)b * NSAMP;
        #pragma unroll
        for (int t = 0; t < 5; ++t) {
            int s = h * 5 + t;
            xp[t] = x + (size_t)sidx[1 + s] * DC;
            ap[t] = aggF + ((size_t)b * 10 + s) * 128;
        }
        float acc[5] = {0, 0, 0, 0, 0};
        hop_gemm<5>(xp, ap, W1r, W2r, acc);
        #pragma unroll
        for (int t = 0; t < 5; ++t) sHop1[h * 5 + t][d] = sigm(acc[t]);

        // hop0 (h==1 half only; wave-uniform branch): LDS-based, 1/11 of the work
        if (h == 1) {
            float acc0 = 0.f;
            for (int k = 0; k < 32; ++k) {
                float4 wa = *(const float4*)(W1r + k * 4);
                float4 wb = *(const float4*)(W2r + k * 4);
                float4 tv = *(const float4*)(sT0 + k * 4);
                float4 av = *(const float4*)(sTbar + k * 4);
                acc0 += wa.x * tv.x + wa.y * tv.y + wa.z * tv.z + wa.w * tv.w
                      + wb.x * av.x + wb.y * av.y + wb.z * av.z + wb.w * av.w;
            }
            sHop0[d] = sigm(acc0);
        }
    }
    __syncthreads();

    // ---- logits: sLog[s] = hop1[s].b2 (s<10), sLog[10] = hop0.b1 ----
    for (int round = 0; round < 2; ++round) {
        int r = round * 8 + g;
        float p = 0.f;
        if (r < 11) {
            const float* src = (r < 10) ? &sHop1[r][0] : &sHop0[0];
            const float* vec = (r < 10) ? (ws + 384) : (ws + 256);  // b2 : b1
            float4 hv = *(const float4*)(src + lane * 4);
            float4 bv = *(const float4*)(vec + lane * 4);
            p = hv.x * bv.x + hv.y * bv.y + hv.z * bv.z + hv.w * bv.w;
        }
        for (int o = 16; o > 0; o >>= 1) p += __shfl_xor(p, o, 32);
        if (r < 11 && lane == 0) sLog[r] = p;
    }
    __syncthreads();

    // ---- beta_h softmax over s ----
    if (tid < 16) {
        float v = (tid < 10) ? lrelu(sLog[10] + sLog[tid]) : -3.4e38f;
        float m = v;
        for (int o = 8; o > 0; o >>= 1) m = fmaxf(m, __shfl_xor(m, o, 16));
        float e = (tid < 10) ? __expf(v - m) : 0.f;
        float ssum = e;
        for (int o = 8; o > 0; o >>= 1) ssum += __shfl_xor(ssum, o, 16);
        if (tid < 10) {
            float bh = e / ssum;
            sBetaH[tid] = bh;
            out[FEA_SZ + (size_t)b * 260 + tid * 26] = bh;
        }
    }
    __syncthreads();

    // ---- hop_h[n] = sum_s beta_h[s] hop1[s][n] ----
    if (tid < 128) {
        float acc = 0.f;
        #pragma unroll
        for (int s = 0; s < 10; ++s) acc += sBetaH[s] * sHop1[s][tid];
        sHopH[tid] = acc;
    }
    __syncthreads();

    // ---- fea_out[l] = sum_d hop_h[d] V1h0[l][d]; out is fea_out^T ----
    if (tid < 128) {
        const float* Vrow = V1h0 + (size_t)tid * DC;
        float acc = 0.f;
        for (int k = 0; k < 32; ++k) {
            float4 w4 = *(const float4*)(Vrow + k * 4);
            acc += w4.x * sHopH[k * 4] + w4.y * sHopH[k * 4 + 1]
                 + w4.z * sHopH[k * 4 + 2] + w4.w * sHopH[k * 4 + 3];
        }
        out[(size_t)tid * 2048 + b] = acc;
    }
}

extern "C" void kernel_launch(void* const* d_in, const int* in_sizes, int n_in,
                              void* d_out, int out_size, void* d_ws, size_t ws_size,
                              hipStream_t stream) {
    const float* x      = (const float*)d_in[0];
    const int*   samples= (const int*)d_in[1];
    const float* V1h1a  = (const float*)d_in[2];
    const float* w1h1   = (const float*)d_in[3];
    const float* V1h0a  = (const float*)d_in[4];
    const float* w1h0   = (const float*)d_in[5];
    const float* V1h1   = (const float*)d_in[6];
    const float* V1h0   = (const float*)d_in[7];
    const float* Whops  = (const float*)d_in[8];
    float* outp = (float*)d_out;
    float* ws   = (float*)d_ws;

    hipLaunchKernelGGL(prep_kernel, dim3(1), dim3(256), 0, stream, V1h1a, w1h1, V1h0a, w1h0, ws);
    hipLaunchKernelGGL(prepWV_kernel, dim3(128), dim3(256), 0, stream, V1h1, Whops, ws);
    hipLaunchKernelGGL(nbr_kernel, dim3(10, 2048), dim3(256), 0, stream,
                       x, samples, ws, ws + WS_AGGF, outp);
    hipLaunchKernelGGL(head_kernel, dim3(2048), dim3(256), 0, stream,
                       x, samples, V1h0, ws, ws + WS_AGGF, outp);
}

// Round 4
// 142.435 us; speedup vs baseline: 1.7628x; 1.7628x over previous
//
#include <hip/hip_runtime.h>
#include <math.h>

#define S1C 10
#define S2C 25
#define DC 128
#define NSAMP 261
#define NBATCH 2048
#define FEA_SZ (128*2048)

// ws layout (floats):
//   [0:128)    a1 = V1h1a^T w1[:128]
//   [128:256)  a2 = V1h1a^T w1[128:]
//   [256:384)  b1 = V1h0a^T w0[:128]
//   [384:512)  b2 = V1h0a^T w0[128:]
//   WS_WVT:  Wt[k][d], k in [0,256): k<128 -> W1V[d][k], k>=128 -> W2V[d][k-128]
//   WS_V0T:  V0t[dd][l] = V1h0[l][dd]
//   WS_TBAR: tbar[b][128]
//   WS_AGGF: aggF[b][s][128]
//   WS_HOP:  hop[b][11][128]  (s<10: hop1[s], s=10: hop0)
#define WS_WVT   512
#define WS_V0T   (WS_WVT + 256*128)
#define WS_TBAR  (WS_V0T + 128*128)
#define WS_AGGF  (WS_TBAR + 2048*128)
#define WS_HOP   (WS_AGGF + 2048*10*128)

__device__ __forceinline__ float lrelu(float v) { return v > 0.f ? v : 0.01f * v; }
__device__ __forceinline__ float sigm(float v) { return 1.f / (1.f + __expf(-v)); }

__global__ void prep_kernel(const float* __restrict__ Vh1a, const float* __restrict__ w1,
                            const float* __restrict__ Vh0a, const float* __restrict__ w0,
                            float* __restrict__ ws) {
    int tid = threadIdx.x;
    for (int o = tid; o < 512; o += 256) {
        int which = o >> 7, n = o & 127;
        const float* V = (which < 2) ? Vh1a : Vh0a;
        const float* w = (which < 2) ? w1 : w0;
        int off = (which & 1) * 128;
        float acc = 0.f;
        for (int l = 0; l < 128; ++l) acc += V[l * 128 + n] * w[off + l];
        ws[o] = acc;
    }
}

// Wt[k][d] = sum_j Whops[d][(k>>7)*128 + j] * V1h1[j][k&127]; grid(128), block(256)
__global__ void prepWVt_kernel(const float* __restrict__ V1h1,
                               const float* __restrict__ Whops,
                               float* __restrict__ ws) {
    int k = blockIdx.x * 2 + (threadIdx.x >> 7);
    int d = threadIdx.x & 127;
    int which = k >> 7, n = k & 127;
    float acc = 0.f;
    for (int j = 0; j < 128; ++j)
        acc += Whops[(size_t)d * 256 + which * 128 + j] * V1h1[(size_t)j * 128 + n];
    ws[WS_WVT + (size_t)k * 128 + d] = acc;
}

// V0t[dd][l] = V1h0[l][dd]; grid(64), block(256)
__global__ void prepV0t_kernel(const float* __restrict__ V1h0, float* __restrict__ ws) {
    int dd = blockIdx.x * 2 + (threadIdx.x >> 7);
    int l = threadIdx.x & 127;
    ws[WS_V0T + (size_t)dd * 128 + l] = V1h0[(size_t)l * 128 + dd];
}

// One block per (b,s): grid = dim3(10, 2048). beta1 + aggF.
__global__ __launch_bounds__(256) void nbr_kernel(
    const float* __restrict__ x, const int* __restrict__ samples,
    const float* __restrict__ ws, float* __restrict__ aggF,
    float* __restrict__ out)
{
    const int s = blockIdx.x, b = blockIdx.y;
    const int tid = threadIdx.x, g = tid >> 5, lane = tid & 31;

    __shared__ __align__(16) float sNbr[25][132];
    __shared__ float sD[26];
    __shared__ float sBeta[25];

    float4 a1v = *(const float4*)(ws + lane * 4);
    float4 a2v = *(const float4*)(ws + 128 + lane * 4);
    const int* sidx = samples + (size_t)b * NSAMP;

    for (int round = 0; round < 4; ++round) {
        int r = round * 8 + g;          // rows 0..24: neighbors; row 25: fea_t1[s]
        float p = 0.f;
        if (r < 26) {
            int node = (r < 25) ? sidx[11 + s * S2C + r] : sidx[1 + s];
            float4 v = *(const float4*)(x + (size_t)node * DC + lane * 4);
            if (r < 25) *(float4*)(&sNbr[r][lane * 4]) = v;
            float4 av = (r < 25) ? a2v : a1v;
            p = v.x * av.x + v.y * av.y + v.z * av.z + v.w * av.w;
        }
        for (int o = 16; o > 0; o >>= 1) p += __shfl_xor(p, o, 32);
        if (r < 26 && lane == 0) sD[r] = p;
    }
    __syncthreads();

    if (tid < 32) {
        float c1 = sD[25];
        float v = (lane < 25) ? lrelu(c1 + sD[lane]) : -3.4e38f;
        float m = v;
        for (int o = 16; o > 0; o >>= 1) m = fmaxf(m, __shfl_xor(m, o, 32));
        float e = (lane < 25) ? __expf(v - m) : 0.f;
        float ssum = e;
        for (int o = 16; o > 0; o >>= 1) ssum += __shfl_xor(ssum, o, 32);
        if (lane < 25) {
            float bt = e / ssum;
            sBeta[lane] = bt;
            out[FEA_SZ + (size_t)b * 260 + s * 26 + 1 + lane] = bt;
        }
    }
    __syncthreads();

    if (tid < 128) {
        float acc = 0.f;
        #pragma unroll
        for (int t = 0; t < 25; ++t) acc += sBeta[t] * sNbr[t][tid];
        aggF[((size_t)b * 10 + s) * 128 + tid] = acc;
    }
}

// One block per b: beta0 + tbar.  tbar[b][n] = sum_s beta0[s] t1[s][n].
__global__ __launch_bounds__(256) void tbar_kernel(
    const float* __restrict__ x, const int* __restrict__ samples,
    const float* __restrict__ ws, float* __restrict__ tbar)
{
    const int b = blockIdx.x;
    const int tid = threadIdx.x, g = tid >> 5, lane = tid & 31;

    __shared__ __align__(16) float sT1[10][132];
    __shared__ float sD1[10], sC0, sBeta0[10];
    __shared__ int sIdx[16];

    if (tid < 11) sIdx[tid] = samples[(size_t)b * NSAMP + tid];
    __syncthreads();

    for (int round = 0; round < 2; ++round) {
        int r = round * 8 + g;
        float p1 = 0.f, p2 = 0.f;
        if (r < 11) {
            int node = (r < 10) ? sIdx[1 + r] : sIdx[0];
            float4 v = *(const float4*)(x + (size_t)node * DC + lane * 4);
            float4 a1v = *(const float4*)(ws + lane * 4);
            float4 a2v = *(const float4*)(ws + 128 + lane * 4);
            if (r < 10) *(float4*)(&sT1[r][lane * 4]) = v;
            p1 = v.x * a1v.x + v.y * a1v.y + v.z * a1v.z + v.w * a1v.w;
            p2 = v.x * a2v.x + v.y * a2v.y + v.z * a2v.z + v.w * a2v.w;
        }
        for (int o = 16; o > 0; o >>= 1) { p1 += __shfl_xor(p1, o, 32); p2 += __shfl_xor(p2, o, 32); }
        if (r < 11 && lane == 0) { if (r < 10) sD1[r] = p2; else sC0 = p1; }
    }
    __syncthreads();

    if (tid < 16) {
        float v = (tid < 10) ? lrelu(sC0 + sD1[tid]) : -3.4e38f;
        float m = v;
        for (int o = 8; o > 0; o >>= 1) m = fmaxf(m, __shfl_xor(m, o, 16));
        float e = (tid < 10) ? __expf(v - m) : 0.f;
        float ssum = e;
        for (int o = 8; o > 0; o >>= 1) ssum += __shfl_xor(ssum, o, 16);
        if (tid < 10) sBeta0[tid] = e / ssum;
    }
    __syncthreads();

    if (tid < 128) {
        float acc = 0.f;
        #pragma unroll
        for (int s = 0; s < 10; ++s) acc += sBeta0[s] * sT1[s][tid];
        tbar[(size_t)b * 128 + tid] = acc;
    }
}

#define FMA8(ACC, S, WL, WH) \
    ACC[0] += (S) * WL.x; ACC[1] += (S) * WL.y; ACC[2] += (S) * WL.z; ACC[3] += (S) * WL.w; \
    ACC[4] += (S) * WH.x; ACC[5] += (S) * WH.y; ACC[6] += (S) * WH.z; ACC[7] += (S) * WH.w;

// GEMM: hop[R][d] = sigm( sum_k act[R][k] * Wt[k][d] ),  R = b*11 + s, K=256.
// act[R] = [ x[node(R)] ; (s<10 ? aggF[b][s] : tbar[b]) ].
// grid(352), block(256); 64 rows/block; thread tile 4 rows x 8 cols.
__global__ __launch_bounds__(256) void hopgemm_kernel(
    const float* __restrict__ x, const int* __restrict__ samples,
    const float* __restrict__ ws, float* __restrict__ hopout)
{
    const int tid = threadIdx.x;
    const int rowbase = blockIdx.x * 64;
    const float* wt = ws + WS_WVT;
    const float* aggF = ws + WS_AGGF;
    const float* tbar = ws + WS_TBAR;

    __shared__ __align__(16) float sAct[64 * 68];

    // staging role: thread stages 16 floats of row sr per chunk
    const int sr = tid >> 2, sq = tid & 3;
    const int R = rowbase + sr;
    const int bb = R / 11, ss = R - bb * 11;
    const int* sidx = samples + (size_t)bb * NSAMP;
    const int node = (ss < 10) ? sidx[1 + ss] : sidx[0];
    const float* xr = x + (size_t)node * DC;
    const float* ar = (ss < 10) ? aggF + ((size_t)bb * 10 + ss) * DC
                                : tbar + (size_t)bb * DC;

    // compute role
    const int d0 = (tid & 15) * 8;
    const int rb = (tid >> 4) * 4;
    float acc0[8], acc1[8], acc2[8], acc3[8];
    #pragma unroll
    for (int i = 0; i < 8; ++i) { acc0[i] = 0.f; acc1[i] = 0.f; acc2[i] = 0.f; acc3[i] = 0.f; }

    for (int c = 0; c < 4; ++c) {
        if (c) __syncthreads();
        const float* src = ((c < 2) ? xr : ar) + (c & 1) * 64;
        #pragma unroll
        for (int i = 0; i < 4; ++i) {
            float4 v = *(const float4*)(src + i * 16 + sq * 4);
            *(float4*)(&sAct[sr * 68 + i * 16 + sq * 4]) = v;
        }
        __syncthreads();
        const float* wtc = wt + (size_t)(c * 64) * 128 + d0;
        for (int kk = 0; kk < 16; ++kk) {
            float4 a0 = *(const float4*)(&sAct[(rb + 0) * 68 + kk * 4]);
            float4 a1 = *(const float4*)(&sAct[(rb + 1) * 68 + kk * 4]);
            float4 a2 = *(const float4*)(&sAct[(rb + 2) * 68 + kk * 4]);
            float4 a3 = *(const float4*)(&sAct[(rb + 3) * 68 + kk * 4]);
            float4 w0l = *(const float4*)(wtc + (size_t)(kk * 4 + 0) * 128);
            float4 w0h = *(const float4*)(wtc + (size_t)(kk * 4 + 0) * 128 + 4);
            float4 w1l = *(const float4*)(wtc + (size_t)(kk * 4 + 1) * 128);
            float4 w1h = *(const float4*)(wtc + (size_t)(kk * 4 + 1) * 128 + 4);
            float4 w2l = *(const float4*)(wtc + (size_t)(kk * 4 + 2) * 128);
            float4 w2h = *(const float4*)(wtc + (size_t)(kk * 4 + 2) * 128 + 4);
            float4 w3l = *(const float4*)(wtc + (size_t)(kk * 4 + 3) * 128);
            float4 w3h = *(const float4*)(wtc + (size_t)(kk * 4 + 3) * 128 + 4);
            FMA8(acc0, a0.x, w0l, w0h); FMA8(acc0, a0.y, w1l, w1h);
            FMA8(acc0, a0.z, w2l, w2h); FMA8(acc0, a0.w, w3l, w3h);
            FMA8(acc1, a1.x, w0l, w0h); FMA8(acc1, a1.y, w1l, w1h);
            FMA8(acc1, a1.z, w2l, w2h); FMA8(acc1, a1.w, w3l, w3h);
            FMA8(acc2, a2.x, w0l, w0h); FMA8(acc2, a2.y, w1l, w1h);
            FMA8(acc2, a2.z, w2l, w2h); FMA8(acc2, a2.w, w3l, w3h);
            FMA8(acc3, a3.x, w0l, w0h); FMA8(acc3, a3.y, w1l, w1h);
            FMA8(acc3, a3.z, w2l, w2h); FMA8(acc3, a3.w, w3l, w3h);
        }
    }

    // write hop rows (sigmoid applied)
    float* hp = hopout + (size_t)(rowbase + rb) * 128 + d0;
    #pragma unroll
    for (int i = 0; i < 8; ++i) { acc0[i] = sigm(acc0[i]); acc1[i] = sigm(acc1[i]);
                                  acc2[i] = sigm(acc2[i]); acc3[i] = sigm(acc3[i]); }
    *(float4*)(hp + 0 * 128)     = make_float4(acc0[0], acc0[1], acc0[2], acc0[3]);
    *(float4*)(hp + 0 * 128 + 4) = make_float4(acc0[4], acc0[5], acc0[6], acc0[7]);
    *(float4*)(hp + 1 * 128)     = make_float4(acc1[0], acc1[1], acc1[2], acc1[3]);
    *(float4*)(hp + 1 * 128 + 4) = make_float4(acc1[4], acc1[5], acc1[6], acc1[7]);
    *(float4*)(hp + 2 * 128)     = make_float4(acc2[0], acc2[1], acc2[2], acc2[3]);
    *(float4*)(hp + 2 * 128 + 4) = make_float4(acc2[4], acc2[5], acc2[6], acc2[7]);
    *(float4*)(hp + 3 * 128)     = make_float4(acc3[0], acc3[1], acc3[2], acc3[3]);
    *(float4*)(hp + 3 * 128 + 4) = make_float4(acc3[4], acc3[5], acc3[6], acc3[7]);
}

// One block per b: logits, beta_h, hop_h, final projection.
__global__ __launch_bounds__(256) void combine_kernel(
    const float* __restrict__ ws, float* __restrict__ out)
{
    const int b = blockIdx.x;
    const int tid = threadIdx.x, g = tid >> 5, lane = tid & 31;
    const float* hop = ws + WS_HOP + (size_t)b * 11 * 128;
    const float* v0t = ws + WS_V0T;

    __shared__ __align__(16) float sHop[11 * 128];
    __shared__ __align__(16) float sHopH[128];
    __shared__ float sLog[12], sBetaH[10];

    for (int i = tid; i < 11 * 32; i += 256)
        *(float4*)(&sHop[i * 4]) = *(const float4*)(hop + i * 4);
    __syncthreads();

    // logits: sLog[s] = hop1[s].b2 (s<10), sLog[10] = hop0.b1
    for (int round = 0; round < 2; ++round) {
        int r = round * 8 + g;
        float p = 0.f;
        if (r < 11) {
            const float* src = &sHop[r * 128];
            const float* vec = (r < 10) ? (ws + 384) : (ws + 256);  // b2 : b1
            float4 hv = *(const float4*)(src + lane * 4);
            float4 bv = *(const float4*)(vec + lane * 4);
            p = hv.x * bv.x + hv.y * bv.y + hv.z * bv.z + hv.w * bv.w;
        }
        for (int o = 16; o > 0; o >>= 1) p += __shfl_xor(p, o, 32);
        if (r < 11 && lane == 0) sLog[r] = p;
    }
    __syncthreads();

    if (tid < 16) {
        float v = (tid < 10) ? lrelu(sLog[10] + sLog[tid]) : -3.4e38f;
        float m = v;
        for (int o = 8; o > 0; o >>= 1) m = fmaxf(m, __shfl_xor(m, o, 16));
        float e = (tid < 10) ? __expf(v - m) : 0.f;
        float ssum = e;
        for (int o = 8; o > 0; o >>= 1) ssum += __shfl_xor(ssum, o, 16);
        if (tid < 10) {
            float bh = e / ssum;
            sBetaH[tid] = bh;
            out[FEA_SZ + (size_t)b * 260 + tid * 26] = bh;
        }
    }
    __syncthreads();

    if (tid < 128) {
        float acc = 0.f;
        #pragma unroll
        for (int s = 0; s < 10; ++s) acc += sBetaH[s] * sHop[s * 128 + tid];
        sHopH[tid] = acc;
    }
    __syncthreads();

    // fea_out[l] = sum_dd hopH[dd] * V0t[dd][l]; out is fea_out^T (coalesced reads)
    if (tid < 128) {
        float acc = 0.f;
        #pragma unroll 8
        for (int dd = 0; dd < 128; ++dd)
            acc += sHopH[dd] * v0t[(size_t)dd * 128 + tid];
        out[(size_t)tid * 2048 + b] = acc;
    }
}

extern "C" void kernel_launch(void* const* d_in, const int* in_sizes, int n_in,
                              void* d_out, int out_size, void* d_ws, size_t ws_size,
                              hipStream_t stream) {
    const float* x      = (const float*)d_in[0];
    const int*   samples= (const int*)d_in[1];
    const float* V1h1a  = (const float*)d_in[2];
    const float* w1h1   = (const float*)d_in[3];
    const float* V1h0a  = (const float*)d_in[4];
    const float* w1h0   = (const float*)d_in[5];
    const float* V1h1   = (const float*)d_in[6];
    const float* V1h0   = (const float*)d_in[7];
    const float* Whops  = (const float*)d_in[8];
    float* outp = (float*)d_out;
    float* ws   = (float*)d_ws;

    hipLaunchKernelGGL(prep_kernel, dim3(1), dim3(256), 0, stream, V1h1a, w1h1, V1h0a, w1h0, ws);
    hipLaunchKernelGGL(prepWVt_kernel, dim3(128), dim3(256), 0, stream, V1h1, Whops, ws);
    hipLaunchKernelGGL(prepV0t_kernel, dim3(64), dim3(256), 0, stream, V1h0, ws);
    hipLaunchKernelGGL(nbr_kernel, dim3(10, 2048), dim3(256), 0, stream,
                       x, samples, ws, ws + WS_AGGF, outp);
    hipLaunchKernelGGL(tbar_kernel, dim3(2048), dim3(256), 0, stream,
                       x, samples, ws, ws + WS_TBAR);
    hipLaunchKernelGGL(hopgemm_kernel, dim3(352), dim3(256), 0, stream,
                       x, samples, ws, ws + WS_HOP);
    hipLaunchKernelGGL(combine_kernel, dim3(2048), dim3(256), 0, stream, ws, outp);
}

// Round 5
// 99.657 us; speedup vs baseline: 2.5195x; 1.4292x over previous
//
#include <hip/hip_runtime.h>
#include <math.h>

#define S1C 10
#define S2C 25
#define DC 128
#define NSAMP 261
#define NBATCH 2048
#define FEA_SZ (128*2048)

// ws layout (floats):
//   [0:128)    a1 = V1h1a^T w1[:128]
//   [128:256)  a2 = V1h1a^T w1[128:]
//   [256:384)  b1 = V1h0a^T w0[:128]
//   [384:512)  b2 = V1h0a^T w0[128:]
//   WS_WVT:  Wt[k][d], k in [0,256): k<128 -> W1V[d][k], k>=128 -> W2V[d][k-128]
//   WS_V0T:  V0t[dd][l] = V1h0[l][dd]
//   WS_AGGF: aggF[b][s][128]
#define WS_WVT   512
#define WS_V0T   (WS_WVT + 256*128)
#define WS_AGGF  (WS_V0T + 128*128)

__device__ __forceinline__ float lrelu(float v) { return v > 0.f ? v : 0.01f * v; }
__device__ __forceinline__ float sigm(float v) { return 1.f / (1.f + __expf(-v)); }
__device__ __forceinline__ float dot4(float4 a, float4 b) {
    return a.x * b.x + a.y * b.y + a.z * b.z + a.w * b.w;
}

// Merged prep: block 0 -> a1/a2/b1/b2; blocks 1..128 -> Wt; blocks 129..192 -> V0t
__global__ void prep_all_kernel(const float* __restrict__ Vh1a, const float* __restrict__ w1,
                                const float* __restrict__ Vh0a, const float* __restrict__ w0,
                                const float* __restrict__ V1h1, const float* __restrict__ Whops,
                                const float* __restrict__ V1h0, float* __restrict__ ws) {
    const int blk = blockIdx.x, tid = threadIdx.x;
    if (blk == 0) {
        for (int o = tid; o < 512; o += 256) {
            int which = o >> 7, n = o & 127;
            const float* V = (which < 2) ? Vh1a : Vh0a;
            const float* w = (which < 2) ? w1 : w0;
            int off = (which & 1) * 128;
            float acc = 0.f;
            for (int l = 0; l < 128; ++l) acc += V[l * 128 + n] * w[off + l];
            ws[o] = acc;
        }
    } else if (blk <= 128) {
        int k = (blk - 1) * 2 + (tid >> 7);
        int d = tid & 127;
        int which = k >> 7, n = k & 127;
        float acc = 0.f;
        for (int j = 0; j < 128; ++j)
            acc += Whops[(size_t)d * 256 + which * 128 + j] * V1h1[(size_t)j * 128 + n];
        ws[WS_WVT + (size_t)k * 128 + d] = acc;
    } else {
        int dd = (blk - 129) * 2 + (tid >> 7);
        int l = tid & 127;
        ws[WS_V0T + (size_t)dd * 128 + l] = V1h0[(size_t)l * 128 + dd];
    }
}

// One block per (b,s): grid = dim3(10, 2048). beta1 + aggF.
// Gather rounds unrolled into independent registers so all 4 loads overlap.
__global__ __launch_bounds__(256) void nbr_kernel(
    const float* __restrict__ x, const int* __restrict__ samples,
    const float* __restrict__ ws, float* __restrict__ aggF,
    float* __restrict__ out)
{
    const int s = blockIdx.x, b = blockIdx.y;
    const int tid = threadIdx.x, g = tid >> 5, lane = tid & 31;

    __shared__ __align__(16) float sNbr[25][132];
    __shared__ float sD[26];
    __shared__ float sBeta[25];

    float4 a1v = *(const float4*)(ws + lane * 4);
    float4 a2v = *(const float4*)(ws + 128 + lane * 4);
    const int* sidx = samples + (size_t)b * NSAMP;

    // rows r = g, 8+g, 16+g (always neighbors), 24+g (g==0: nbr 24, g==1: t1[s])
    const int r3 = 24 + g;
    const bool has3 = (g < 2);
    int n0 = sidx[11 + s * S2C + g];
    int n1 = sidx[11 + s * S2C + 8 + g];
    int n2 = sidx[11 + s * S2C + 16 + g];
    int n3 = has3 ? ((g == 0) ? sidx[11 + s * S2C + 24] : sidx[1 + s]) : 0;

    float4 v0 = *(const float4*)(x + (size_t)n0 * DC + lane * 4);
    float4 v1 = *(const float4*)(x + (size_t)n1 * DC + lane * 4);
    float4 v2 = *(const float4*)(x + (size_t)n2 * DC + lane * 4);
    float4 v3 = make_float4(0.f, 0.f, 0.f, 0.f);
    if (has3) v3 = *(const float4*)(x + (size_t)n3 * DC + lane * 4);

    *(float4*)(&sNbr[g][lane * 4]) = v0;
    *(float4*)(&sNbr[8 + g][lane * 4]) = v1;
    *(float4*)(&sNbr[16 + g][lane * 4]) = v2;
    if (g == 0) *(float4*)(&sNbr[24][lane * 4]) = v3;

    float p0 = dot4(v0, a2v);
    float p1 = dot4(v1, a2v);
    float p2 = dot4(v2, a2v);
    float p3 = has3 ? dot4(v3, (g == 0) ? a2v : a1v) : 0.f;
    #pragma unroll
    for (int o = 16; o > 0; o >>= 1) {
        p0 += __shfl_xor(p0, o, 32);
        p1 += __shfl_xor(p1, o, 32);
        p2 += __shfl_xor(p2, o, 32);
        p3 += __shfl_xor(p3, o, 32);
    }
    if (lane == 0) {
        sD[g] = p0; sD[8 + g] = p1; sD[16 + g] = p2;
        if (has3) sD[r3] = p3;
    }
    __syncthreads();

    if (tid < 32) {
        float c1 = sD[25];
        float v = (lane < 25) ? lrelu(c1 + sD[lane]) : -3.4e38f;
        float m = v;
        for (int o = 16; o > 0; o >>= 1) m = fmaxf(m, __shfl_xor(m, o, 32));
        float e = (lane < 25) ? __expf(v - m) : 0.f;
        float ssum = e;
        for (int o = 16; o > 0; o >>= 1) ssum += __shfl_xor(ssum, o, 32);
        if (lane < 25) {
            float bt = e / ssum;
            sBeta[lane] = bt;
            out[FEA_SZ + (size_t)b * 260 + s * 26 + 1 + lane] = bt;
        }
    }
    __syncthreads();

    if (tid < 128) {
        float acc = 0.f;
        #pragma unroll
        for (int t = 0; t < 25; ++t) acc += sBeta[t] * sNbr[t][tid];
        aggF[((size_t)b * 10 + s) * 128 + tid] = acc;
    }
}

// Fused: beta0/tbar + hop GEMM + logits/beta_h/hopH + final projection.
// grid(512): each block owns 4 complete b's (44 GEMM rows).
// Thread layout: bl = tid>>6 (wave == one b), cg = tid&63 (2 output cols).
__global__ __launch_bounds__(256) void hopfused_kernel(
    const float* __restrict__ x, const int* __restrict__ samples,
    const float* __restrict__ ws, float* __restrict__ out)
{
    const int b0 = blockIdx.x * 4;
    const int tid = threadIdx.x;
    const int bl = tid >> 6, cg = tid & 63;
    const int g = tid >> 5, lane = tid & 31;
    const int c0 = cg * 2;

    __shared__ __align__(16) float sX[44][128];
    __shared__ __align__(16) float sTbar[4][128];
    __shared__ __align__(16) float sHopH[4][128];
    __shared__ float sD[44];
    __shared__ float sBeta0[4][10];
    __shared__ int sNode[44];

    if (tid < 44) {
        int bb = tid / 11, s = tid - bb * 11;
        sNode[tid] = (s < 10) ? samples[(size_t)(b0 + bb) * NSAMP + 1 + s]
                              : samples[(size_t)(b0 + bb) * NSAMP];
    }
    __syncthreads();

    // gather 44 x-rows (independent iterations -> overlapped loads)
    for (int i = tid; i < 44 * 32; i += 256) {
        int row = i >> 5, seg = i & 31;
        *(float4*)(&sX[row][seg * 4]) =
            *(const float4*)(x + (size_t)sNode[row] * DC + seg * 4);
    }
    __syncthreads();

    // per-row att dots: s<10 -> d1 = t1.a2 ; s==10 -> c0 = t0.a1
    for (int rd = 0; rd < 6; ++rd) {
        int r = rd * 8 + g;
        float p = 0.f;
        if (r < 44) {
            int s = r % 11;
            const float* av = ws + ((s < 10) ? 128 : 0);
            float4 v = *(const float4*)(&sX[r][lane * 4]);
            float4 a = *(const float4*)(av + lane * 4);
            p = dot4(v, a);
        }
        for (int o = 16; o > 0; o >>= 1) p += __shfl_xor(p, o, 32);
        if (r < 44 && lane == 0) sD[r] = p;
    }
    __syncthreads();

    // beta0 per bl
    if (tid < 64) {
        int bb = tid >> 4, j = tid & 15;
        float cc = sD[bb * 11 + 10];
        float v = (j < 10) ? lrelu(cc + sD[bb * 11 + j]) : -3.4e38f;
        float m = v;
        for (int o = 8; o > 0; o >>= 1) m = fmaxf(m, __shfl_xor(m, o, 16));
        float e = (j < 10) ? __expf(v - m) : 0.f;
        float ss = e;
        for (int o = 8; o > 0; o >>= 1) ss += __shfl_xor(ss, o, 16);
        if (j < 10) sBeta0[bb][j] = e / ss;
    }
    __syncthreads();

    // tbar[bb][n] = sum_s beta0[bb][s] * t1[bb][s][n]
    for (int o = tid; o < 512; o += 256) {
        int bb = o >> 7, n = o & 127;
        float acc = 0.f;
        #pragma unroll
        for (int s = 0; s < 10; ++s) acc += sBeta0[bb][s] * sX[bb * 11 + s][n];
        sTbar[bb][n] = acc;
    }
    __syncthreads();

    const float* wt = ws + WS_WVT;
    float acc[11][2];
    #pragma unroll
    for (int s = 0; s < 11; ++s) { acc[s][0] = 0.f; acc[s][1] = 0.f; }

    // GEMM phase A: k in [0,128) (x part, W1V)
    for (int k = 0; k < 128; k += 4) {
        float4 a[11];
        #pragma unroll
        for (int s = 0; s < 11; ++s) a[s] = *(const float4*)(&sX[bl * 11 + s][k]);
        float2 w0 = *(const float2*)(wt + (size_t)(k + 0) * 128 + c0);
        float2 w1 = *(const float2*)(wt + (size_t)(k + 1) * 128 + c0);
        float2 w2 = *(const float2*)(wt + (size_t)(k + 2) * 128 + c0);
        float2 w3 = *(const float2*)(wt + (size_t)(k + 3) * 128 + c0);
        #pragma unroll
        for (int s = 0; s < 11; ++s) {
            acc[s][0] += a[s].x * w0.x + a[s].y * w1.x + a[s].z * w2.x + a[s].w * w3.x;
            acc[s][1] += a[s].x * w0.y + a[s].y * w1.y + a[s].z * w2.y + a[s].w * w3.y;
        }
    }
    __syncthreads();

    // restage sX with agg rows: s<10 -> aggF[b][s], s==10 -> tbar[bb]
    for (int i = tid; i < 44 * 32; i += 256) {
        int row = i >> 5, seg = i & 31;
        int bb = row / 11, s = row - bb * 11;
        float4 v;
        if (s < 10) v = *(const float4*)(ws + WS_AGGF + ((size_t)(b0 + bb) * 10 + s) * DC + seg * 4);
        else        v = *(const float4*)(&sTbar[bb][seg * 4]);
        *(float4*)(&sX[row][seg * 4]) = v;
    }
    __syncthreads();

    // GEMM phase B: k in [0,128) (agg part, W2V at wt row 128+k)
    for (int k = 0; k < 128; k += 4) {
        float4 a[11];
        #pragma unroll
        for (int s = 0; s < 11; ++s) a[s] = *(const float4*)(&sX[bl * 11 + s][k]);
        float2 w0 = *(const float2*)(wt + (size_t)(128 + k + 0) * 128 + c0);
        float2 w1 = *(const float2*)(wt + (size_t)(128 + k + 1) * 128 + c0);
        float2 w2 = *(const float2*)(wt + (size_t)(128 + k + 2) * 128 + c0);
        float2 w3 = *(const float2*)(wt + (size_t)(128 + k + 3) * 128 + c0);
        #pragma unroll
        for (int s = 0; s < 11; ++s) {
            acc[s][0] += a[s].x * w0.x + a[s].y * w1.x + a[s].z * w2.x + a[s].w * w3.x;
            acc[s][1] += a[s].x * w0.y + a[s].y * w1.y + a[s].z * w2.y + a[s].w * w3.y;
        }
    }

    // sigmoid -> hop values (2 cols x 11 rows in registers)
    float h[11][2];
    #pragma unroll
    for (int s = 0; s < 11; ++s) { h[s][0] = sigm(acc[s][0]); h[s][1] = sigm(acc[s][1]); }

    // logits: lg[s] = hop1[s].b2 (s<10), lg[10] = hop0.b1 ; full-wave reduce
    const float* b1v = ws + 256;
    const float* b2v = ws + 384;
    float lg[11];
    #pragma unroll
    for (int s = 0; s < 11; ++s) {
        const float* vb = (s < 10) ? b2v : b1v;
        float p = h[s][0] * vb[c0] + h[s][1] * vb[c0 + 1];
        #pragma unroll
        for (int o = 32; o > 0; o >>= 1) p += __shfl_xor(p, o, 64);
        lg[s] = p;
    }

    // beta_h softmax (replicated across the wave's 64 lanes)
    float lv[10], bh[10];
    float mm = -3.4e38f;
    #pragma unroll
    for (int s = 0; s < 10; ++s) { lv[s] = lrelu(lg[10] + lg[s]); mm = fmaxf(mm, lv[s]); }
    float ssum = 0.f;
    #pragma unroll
    for (int s = 0; s < 10; ++s) { bh[s] = __expf(lv[s] - mm); ssum += bh[s]; }
    float inv = 1.f / ssum;
    const int b = b0 + bl;
    #pragma unroll
    for (int s = 0; s < 10; ++s)
        if (cg == s) out[FEA_SZ + (size_t)b * 260 + s * 26] = bh[s] * inv;

    // hopH[c0..c0+1] = sum_s beta_h[s] * hop1[s][c]
    float h0 = 0.f, h1 = 0.f;
    #pragma unroll
    for (int s = 0; s < 10; ++s) {
        float w = bh[s] * inv;
        h0 += w * h[s][0];
        h1 += w * h[s][1];
    }
    sHopH[bl][c0] = h0;
    sHopH[bl][c0 + 1] = h1;
    __syncthreads();

    // fea_out[l] = sum_dd hopH[dd] * V0t[dd][l]; out is fea_out^T
    const float* v0t = ws + WS_V0T;
    float o0 = 0.f, o1 = 0.f;
    #pragma unroll 8
    for (int dd = 0; dd < 128; ++dd) {
        float hv = sHopH[bl][dd];
        float2 vv = *(const float2*)(v0t + (size_t)dd * 128 + c0);
        o0 += hv * vv.x;
        o1 += hv * vv.y;
    }
    out[(size_t)c0 * 2048 + b] = o0;
    out[(size_t)(c0 + 1) * 2048 + b] = o1;
}

extern "C" void kernel_launch(void* const* d_in, const int* in_sizes, int n_in,
                              void* d_out, int out_size, void* d_ws, size_t ws_size,
                              hipStream_t stream) {
    const float* x      = (const float*)d_in[0];
    const int*   samples= (const int*)d_in[1];
    const float* V1h1a  = (const float*)d_in[2];
    const float* w1h1   = (const float*)d_in[3];
    const float* V1h0a  = (const float*)d_in[4];
    const float* w1h0   = (const float*)d_in[5];
    const float* V1h1   = (const float*)d_in[6];
    const float* V1h0   = (const float*)d_in[7];
    const float* Whops  = (const float*)d_in[8];
    float* outp = (float*)d_out;
    float* ws   = (float*)d_ws;

    hipLaunchKernelGGL(prep_all_kernel, dim3(193), dim3(256), 0, stream,
                       V1h1a, w1h1, V1h0a, w1h0, V1h1, Whops, V1h0, ws);
    hipLaunchKernelGGL(nbr_kernel, dim3(10, 2048), dim3(256), 0, stream,
                       x, samples, ws, ws + WS_AGGF, outp);
    hipLaunchKernelGGL(hopfused_kernel, dim3(512), dim3(256), 0, stream,
                       x, samples, ws, outp);
}

// Round 6
// 98.832 us; speedup vs baseline: 2.5405x; 1.0083x over previous
//
#include <hip/hip_runtime.h>
#include <math.h>

#define S1C 10
#define S2C 25
#define DC 128
#define NSAMP 261
#define NBATCH 2048
#define FEA_SZ (128*2048)

// ws layout (floats):
//   [0:128)    a1 = V1h1a^T w1[:128]
//   [128:256)  a2 = V1h1a^T w1[128:]
//   [256:384)  b1 = V1h0a^T w0[:128]
//   [384:512)  b2 = V1h0a^T w0[128:]
//   WS_WVT:  Wt[k][d], k in [0,256): k<128 -> W1V[d][k], k>=128 -> W2V[d][k-128]
//   WS_V0T:  V0t[dd][l] = V1h0[l][dd]
//   WS_AGGF: aggF[b][s][128]
#define WS_WVT   512
#define WS_V0T   (WS_WVT + 256*128)
#define WS_AGGF  (WS_V0T + 128*128)

__device__ __forceinline__ float lrelu(float v) { return v > 0.f ? v : 0.01f * v; }
__device__ __forceinline__ float sigm(float v) { return 1.f / (1.f + __expf(-v)); }
__device__ __forceinline__ float dot4(float4 a, float4 b) {
    return a.x * b.x + a.y * b.y + a.z * b.z + a.w * b.w;
}

// Merged prep: block 0 -> a1/a2/b1/b2; blocks 1..128 -> Wt; blocks 129..192 -> V0t
__global__ void prep_all_kernel(const float* __restrict__ Vh1a, const float* __restrict__ w1,
                                const float* __restrict__ Vh0a, const float* __restrict__ w0,
                                const float* __restrict__ V1h1, const float* __restrict__ Whops,
                                const float* __restrict__ V1h0, float* __restrict__ ws) {
    const int blk = blockIdx.x, tid = threadIdx.x;
    if (blk == 0) {
        for (int o = tid; o < 512; o += 256) {
            int which = o >> 7, n = o & 127;
            const float* V = (which < 2) ? Vh1a : Vh0a;
            const float* w = (which < 2) ? w1 : w0;
            int off = (which & 1) * 128;
            float acc = 0.f;
            for (int l = 0; l < 128; ++l) acc += V[l * 128 + n] * w[off + l];
            ws[o] = acc;
        }
    } else if (blk <= 128) {
        int k = (blk - 1) * 2 + (tid >> 7);
        int d = tid & 127;
        int which = k >> 7, n = k & 127;
        float acc = 0.f;
        for (int j = 0; j < 128; ++j)
            acc += Whops[(size_t)d * 256 + which * 128 + j] * V1h1[(size_t)j * 128 + n];
        ws[WS_WVT + (size_t)k * 128 + d] = acc;
    } else {
        int dd = (blk - 129) * 2 + (tid >> 7);
        int l = tid & 127;
        ws[WS_V0T + (size_t)dd * 128 + l] = V1h0[(size_t)l * 128 + dd];
    }
}

// One block per (b,s): grid = dim3(10, 2048). beta1 + aggF. (unchanged from R5)
__global__ __launch_bounds__(256) void nbr_kernel(
    const float* __restrict__ x, const int* __restrict__ samples,
    const float* __restrict__ ws, float* __restrict__ aggF,
    float* __restrict__ out)
{
    const int s = blockIdx.x, b = blockIdx.y;
    const int tid = threadIdx.x, g = tid >> 5, lane = tid & 31;

    __shared__ __align__(16) float sNbr[25][132];
    __shared__ float sD[26];
    __shared__ float sBeta[25];

    float4 a1v = *(const float4*)(ws + lane * 4);
    float4 a2v = *(const float4*)(ws + 128 + lane * 4);
    const int* sidx = samples + (size_t)b * NSAMP;

    const bool has3 = (g < 2);
    int n0 = sidx[11 + s * S2C + g];
    int n1 = sidx[11 + s * S2C + 8 + g];
    int n2 = sidx[11 + s * S2C + 16 + g];
    int n3 = has3 ? ((g == 0) ? sidx[11 + s * S2C + 24] : sidx[1 + s]) : 0;

    float4 v0 = *(const float4*)(x + (size_t)n0 * DC + lane * 4);
    float4 v1 = *(const float4*)(x + (size_t)n1 * DC + lane * 4);
    float4 v2 = *(const float4*)(x + (size_t)n2 * DC + lane * 4);
    float4 v3 = make_float4(0.f, 0.f, 0.f, 0.f);
    if (has3) v3 = *(const float4*)(x + (size_t)n3 * DC + lane * 4);

    *(float4*)(&sNbr[g][lane * 4]) = v0;
    *(float4*)(&sNbr[8 + g][lane * 4]) = v1;
    *(float4*)(&sNbr[16 + g][lane * 4]) = v2;
    if (g == 0) *(float4*)(&sNbr[24][lane * 4]) = v3;

    float p0 = dot4(v0, a2v);
    float p1 = dot4(v1, a2v);
    float p2 = dot4(v2, a2v);
    float p3 = has3 ? dot4(v3, (g == 0) ? a2v : a1v) : 0.f;
    #pragma unroll
    for (int o = 16; o > 0; o >>= 1) {
        p0 += __shfl_xor(p0, o, 32);
        p1 += __shfl_xor(p1, o, 32);
        p2 += __shfl_xor(p2, o, 32);
        p3 += __shfl_xor(p3, o, 32);
    }
    if (lane == 0) {
        sD[g] = p0; sD[8 + g] = p1; sD[16 + g] = p2;
        if (has3) sD[24 + g] = p3;
    }
    __syncthreads();

    if (tid < 32) {
        float c1 = sD[25];
        float v = (lane < 25) ? lrelu(c1 + sD[lane]) : -3.4e38f;
        float m = v;
        for (int o = 16; o > 0; o >>= 1) m = fmaxf(m, __shfl_xor(m, o, 32));
        float e = (lane < 25) ? __expf(v - m) : 0.f;
        float ssum = e;
        for (int o = 16; o > 0; o >>= 1) ssum += __shfl_xor(ssum, o, 32);
        if (lane < 25) {
            float bt = e / ssum;
            sBeta[lane] = bt;
            out[FEA_SZ + (size_t)b * 260 + s * 26 + 1 + lane] = bt;
        }
    }
    __syncthreads();

    if (tid < 128) {
        float acc = 0.f;
        #pragma unroll
        for (int t = 0; t < 25; ++t) acc += sBeta[t] * sNbr[t][tid];
        aggF[((size_t)b * 10 + s) * 128 + tid] = acc;
    }
}

// Fused head: 2 b's per block, grid 1024.
// Waves: w = tid>>6; bw = w>>1 (which b), ch = w&1 (which 64-col half).
// Lane: kh = lane>>5 (K half), cg = lane&31 (col pair); c0 = ch*64 + cg*2.
__global__ __launch_bounds__(256, 3) void hopfused_kernel(
    const float* __restrict__ x, const int* __restrict__ samples,
    const float* __restrict__ ws, float* __restrict__ out)
{
    const int b0 = blockIdx.x * 2;
    const int tid = threadIdx.x;
    const int g = tid >> 5, lane = tid & 63;
    const int w = tid >> 6;
    const int bw = w >> 1, ch = w & 1;
    const int kh = (tid & 63) >> 5, cg = tid & 31;
    const int c0 = ch * 64 + cg * 2;
    const int rb = bw * 11;

    __shared__ __align__(16) float sX[22][128];
    __shared__ __align__(16) float sTbar[2][128];
    __shared__ __align__(16) float sHopH[2][128];
    __shared__ float sD[22];
    __shared__ float sBeta0[2][10];
    __shared__ float sLogW[2][2][11];
    __shared__ int sNode[22];

    if (tid < 22) {
        int bb = tid / 11, s = tid - bb * 11;
        sNode[tid] = (s < 10) ? samples[(size_t)(b0 + bb) * NSAMP + 1 + s]
                              : samples[(size_t)(b0 + bb) * NSAMP];
    }
    __syncthreads();

    // gather 22 x-rows
    for (int i = tid; i < 22 * 32; i += 256) {
        int row = i >> 5, seg = i & 31;
        *(float4*)(&sX[row][seg * 4]) =
            *(const float4*)(x + (size_t)sNode[row] * DC + seg * 4);
    }
    __syncthreads();

    // att dots: s<10 -> t1.a2 ; s==10 -> t0.a1
    {
        int r = g;  // one round: g in 0..7 covers 8; need 3 rounds for 22
        for (int rd = 0; rd < 3; ++rd, r += 8) {
            float p = 0.f;
            int ln = tid & 31;
            if (r < 22) {
                int s = (r < 11) ? r : r - 11;
                const float* av = ws + ((s < 10) ? 128 : 0);
                float4 v = *(const float4*)(&sX[r][ln * 4]);
                float4 a = *(const float4*)(av + ln * 4);
                p = dot4(v, a);
            }
            for (int o = 16; o > 0; o >>= 1) p += __shfl_xor(p, o, 32);
            if (r < 22 && ln == 0) sD[r] = p;
        }
    }
    __syncthreads();

    // beta0 per bb
    if (tid < 32) {
        int bb = tid >> 4, j = tid & 15;
        float cc = sD[bb * 11 + 10];
        float v = (j < 10) ? lrelu(cc + sD[bb * 11 + j]) : -3.4e38f;
        float m = v;
        for (int o = 8; o > 0; o >>= 1) m = fmaxf(m, __shfl_xor(m, o, 16));
        float e = (j < 10) ? __expf(v - m) : 0.f;
        float ss = e;
        for (int o = 8; o > 0; o >>= 1) ss += __shfl_xor(ss, o, 16);
        if (j < 10) sBeta0[bb][j] = e / ss;
    }
    __syncthreads();

    // tbar[bb][n]
    {
        int bb = tid >> 7, n = tid & 127;
        float acc = 0.f;
        #pragma unroll
        for (int s = 0; s < 10; ++s) acc += sBeta0[bb][s] * sX[bb * 11 + s][n];
        sTbar[bb][n] = acc;
    }
    __syncthreads();

    const float* wt = ws + WS_WVT;
    float accx[11], accy[11];
    #pragma unroll
    for (int s = 0; s < 11; ++s) { accx[s] = 0.f; accy[s] = 0.f; }

#define GEMM_PHASE(WB)                                                          \
    _Pragma("unroll 2")                                                         \
    for (int kk = 0; kk < 16; ++kk) {                                           \
        const int k = (kh << 6) + (kk << 2);                                    \
        float2 w0 = *(const float2*)((WB) + (size_t)(k + 0) * 128 + c0);        \
        float2 w1 = *(const float2*)((WB) + (size_t)(k + 1) * 128 + c0);        \
        float2 w2 = *(const float2*)((WB) + (size_t)(k + 2) * 128 + c0);        \
        float2 w3 = *(const float2*)((WB) + (size_t)(k + 3) * 128 + c0);        \
        _Pragma("unroll")                                                       \
        for (int s = 0; s < 11; ++s) {                                          \
            float4 a = *(const float4*)(&sX[rb + s][k]);                        \
            accx[s] += a.x * w0.x + a.y * w1.x + a.z * w2.x + a.w * w3.x;       \
            accy[s] += a.x * w0.y + a.y * w1.y + a.z * w2.y + a.w * w3.y;       \
        }                                                                       \
    }

    // phase A: x rows vs W1V
    GEMM_PHASE(wt)
    __syncthreads();

    // restage sX with agg rows: s<10 -> aggF[b][s], s==10 -> tbar[bb]
    for (int i = tid; i < 22 * 32; i += 256) {
        int row = i >> 5, seg = i & 31;
        int bb = row / 11, s = row - bb * 11;
        float4 v;
        if (s < 10) v = *(const float4*)(ws + WS_AGGF + ((size_t)(b0 + bb) * 10 + s) * DC + seg * 4);
        else        v = *(const float4*)(&sTbar[bb][seg * 4]);
        *(float4*)(&sX[row][seg * 4]) = v;
    }
    __syncthreads();

    // phase B: agg rows vs W2V
    GEMM_PHASE(wt + (size_t)128 * 128)

    // combine K-halves: lanes kh=0/1 hold complementary partials
    #pragma unroll
    for (int s = 0; s < 11; ++s) {
        accx[s] += __shfl_xor(accx[s], 32, 64);
        accy[s] += __shfl_xor(accy[s], 32, 64);
    }

    float hx[11], hy[11];
    #pragma unroll
    for (int s = 0; s < 11; ++s) { hx[s] = sigm(accx[s]); hy[s] = sigm(accy[s]); }

    // logit partials: reduce over cg (covers this wave's 64 cols)
    {
        const float* b1v = ws + 256;
        const float* b2v = ws + 384;
        #pragma unroll
        for (int s = 0; s < 11; ++s) {
            const float* vb = (s < 10) ? b2v : b1v;
            float p = hx[s] * vb[c0] + hy[s] * vb[c0 + 1];
            #pragma unroll
            for (int o = 16; o > 0; o >>= 1) p += __shfl_xor(p, o, 64);
            if (lane == 0) sLogW[bw][ch][s] = p;
        }
    }
    __syncthreads();

    // beta_h (computed redundantly per thread from LDS partials)
    float bh[10];
    {
        float lg10 = sLogW[bw][0][10] + sLogW[bw][1][10];
        float mm = -3.4e38f;
        float lv[10];
        #pragma unroll
        for (int s = 0; s < 10; ++s) {
            float lgs = sLogW[bw][0][s] + sLogW[bw][1][s];
            lv[s] = lrelu(lg10 + lgs);
            mm = fmaxf(mm, lv[s]);
        }
        float ssum = 0.f;
        #pragma unroll
        for (int s = 0; s < 10; ++s) { bh[s] = __expf(lv[s] - mm); ssum += bh[s]; }
        float inv = 1.f / ssum;
        #pragma unroll
        for (int s = 0; s < 10; ++s) bh[s] *= inv;
    }
    if (ch == 0 && lane < 10)
        out[FEA_SZ + (size_t)(b0 + bw) * 260 + lane * 26] = bh[lane];

    // hopH cols
    {
        float h0 = 0.f, h1 = 0.f;
        #pragma unroll
        for (int s = 0; s < 10; ++s) { h0 += bh[s] * hx[s]; h1 += bh[s] * hy[s]; }
        if (kh == 0) { sHopH[bw][c0] = h0; sHopH[bw][c0 + 1] = h1; }
    }
    __syncthreads();

    // fea_out[c] for both b's: out is fea_out^T
    {
        const float* v0t = ws + WS_V0T;
        int c = tid & 127, bb = tid >> 7;
        float acc = 0.f;
        for (int dd = 0; dd < 128; dd += 4) {
            float4 hh = *(const float4*)(&sHopH[bb][dd]);
            acc += hh.x * v0t[(size_t)(dd + 0) * 128 + c]
                 + hh.y * v0t[(size_t)(dd + 1) * 128 + c]
                 + hh.z * v0t[(size_t)(dd + 2) * 128 + c]
                 + hh.w * v0t[(size_t)(dd + 3) * 128 + c];
        }
        out[(size_t)c * 2048 + b0 + bb] = acc;
    }
}

extern "C" void kernel_launch(void* const* d_in, const int* in_sizes, int n_in,
                              void* d_out, int out_size, void* d_ws, size_t ws_size,
                              hipStream_t stream) {
    const float* x      = (const float*)d_in[0];
    const int*   samples= (const int*)d_in[1];
    const float* V1h1a  = (const float*)d_in[2];
    const float* w1h1   = (const float*)d_in[3];
    const float* V1h0a  = (const float*)d_in[4];
    const float* w1h0   = (const float*)d_in[5];
    const float* V1h1   = (const float*)d_in[6];
    const float* V1h0   = (const float*)d_in[7];
    const float* Whops  = (const float*)d_in[8];
    float* outp = (float*)d_out;
    float* ws   = (float*)d_ws;

    hipLaunchKernelGGL(prep_all_kernel, dim3(193), dim3(256), 0, stream,
                       V1h1a, w1h1, V1h0a, w1h0, V1h1, Whops, V1h0, ws);
    hipLaunchKernelGGL(nbr_kernel, dim3(10, 2048), dim3(256), 0, stream,
                       x, samples, ws, ws + WS_AGGF, outp);
    hipLaunchKernelGGL(hopfused_kernel, dim3(1024), dim3(256), 0, stream,
                       x, samples, ws, outp);
}

// Round 7
// 93.561 us; speedup vs baseline: 2.6837x; 1.0563x over previous
//
#include <hip/hip_runtime.h>
#include <math.h>

#define S1C 10
#define S2C 25
#define DC 128
#define NSAMP 261
#define NBATCH 2048
#define FEA_SZ (128*2048)

// ws layout (floats):
//   [0:128)    a1 = V1h1a^T w1[:128]
//   [128:256)  a2 = V1h1a^T w1[128:]
//   [256:384)  b1 = V1h0a^T w0[:128]
//   [384:512)  b2 = V1h0a^T w0[128:]
//   WS_WVT:  Wt[k][d], k in [0,256): k<128 -> W1V[d][k], k>=128 -> W2V[d][k-128]
//   WS_V0T:  V0t[dd][l] = V1h0[l][dd]
//   WS_AGGF: aggF[b][s][128]
#define WS_WVT   512
#define WS_V0T   (WS_WVT + 256*128)
#define WS_AGGF  (WS_V0T + 128*128)

__device__ __forceinline__ float lrelu(float v) { return v > 0.f ? v : 0.01f * v; }
__device__ __forceinline__ float sigm(float v) { return 1.f / (1.f + __expf(-v)); }
__device__ __forceinline__ float dot4(float4 a, float4 b) {
    return a.x * b.x + a.y * b.y + a.z * b.z + a.w * b.w;
}

// Merged prep: block 0 -> a1/a2/b1/b2; blocks 1..128 -> Wt; blocks 129..192 -> V0t
__global__ void prep_all_kernel(const float* __restrict__ Vh1a, const float* __restrict__ w1,
                                const float* __restrict__ Vh0a, const float* __restrict__ w0,
                                const float* __restrict__ V1h1, const float* __restrict__ Whops,
                                const float* __restrict__ V1h0, float* __restrict__ ws) {
    const int blk = blockIdx.x, tid = threadIdx.x;
    if (blk == 0) {
        for (int o = tid; o < 512; o += 256) {
            int which = o >> 7, n = o & 127;
            const float* V = (which < 2) ? Vh1a : Vh0a;
            const float* w = (which < 2) ? w1 : w0;
            int off = (which & 1) * 128;
            float acc = 0.f;
            for (int l = 0; l < 128; ++l) acc += V[l * 128 + n] * w[off + l];
            ws[o] = acc;
        }
    } else if (blk <= 128) {
        int k = (blk - 1) * 2 + (tid >> 7);
        int d = tid & 127;
        int which = k >> 7, n = k & 127;
        float acc = 0.f;
        for (int j = 0; j < 128; ++j)
            acc += Whops[(size_t)d * 256 + which * 128 + j] * V1h1[(size_t)j * 128 + n];
        ws[WS_WVT + (size_t)k * 128 + d] = acc;
    } else {
        int dd = (blk - 129) * 2 + (tid >> 7);
        int l = tid & 127;
        ws[WS_V0T + (size_t)dd * 128 + l] = V1h0[(size_t)l * 128 + dd];
    }
}

// One block per (b,s): grid = dim3(10, 2048). beta1 + aggF.
__global__ __launch_bounds__(256) void nbr_kernel(
    const float* __restrict__ x, const int* __restrict__ samples,
    const float* __restrict__ ws, float* __restrict__ aggF,
    float* __restrict__ out)
{
    const int s = blockIdx.x, b = blockIdx.y;
    const int tid = threadIdx.x, g = tid >> 5, lane = tid & 31;

    __shared__ __align__(16) float sNbr[25][132];
    __shared__ float sD[26];
    __shared__ float sBeta[25];

    float4 a1v = *(const float4*)(ws + lane * 4);
    float4 a2v = *(const float4*)(ws + 128 + lane * 4);
    const int* sidx = samples + (size_t)b * NSAMP;

    const bool has3 = (g < 2);
    int n0 = sidx[11 + s * S2C + g];
    int n1 = sidx[11 + s * S2C + 8 + g];
    int n2 = sidx[11 + s * S2C + 16 + g];
    int n3 = has3 ? ((g == 0) ? sidx[11 + s * S2C + 24] : sidx[1 + s]) : 0;

    float4 v0 = *(const float4*)(x + (size_t)n0 * DC + lane * 4);
    float4 v1 = *(const float4*)(x + (size_t)n1 * DC + lane * 4);
    float4 v2 = *(const float4*)(x + (size_t)n2 * DC + lane * 4);
    float4 v3 = make_float4(0.f, 0.f, 0.f, 0.f);
    if (has3) v3 = *(const float4*)(x + (size_t)n3 * DC + lane * 4);

    *(float4*)(&sNbr[g][lane * 4]) = v0;
    *(float4*)(&sNbr[8 + g][lane * 4]) = v1;
    *(float4*)(&sNbr[16 + g][lane * 4]) = v2;
    if (g == 0) *(float4*)(&sNbr[24][lane * 4]) = v3;

    float p0 = dot4(v0, a2v);
    float p1 = dot4(v1, a2v);
    float p2 = dot4(v2, a2v);
    float p3 = has3 ? dot4(v3, (g == 0) ? a2v : a1v) : 0.f;
    #pragma unroll
    for (int o = 16; o > 0; o >>= 1) {
        p0 += __shfl_xor(p0, o, 32);
        p1 += __shfl_xor(p1, o, 32);
        p2 += __shfl_xor(p2, o, 32);
        p3 += __shfl_xor(p3, o, 32);
    }
    if (lane == 0) {
        sD[g] = p0; sD[8 + g] = p1; sD[16 + g] = p2;
        if (has3) sD[24 + g] = p3;
    }
    __syncthreads();

    if (tid < 32) {
        float c1 = sD[25];
        float v = (lane < 25) ? lrelu(c1 + sD[lane]) : -3.4e38f;
        float m = v;
        for (int o = 16; o > 0; o >>= 1) m = fmaxf(m, __shfl_xor(m, o, 32));
        float e = (lane < 25) ? __expf(v - m) : 0.f;
        float ssum = e;
        for (int o = 16; o > 0; o >>= 1) ssum += __shfl_xor(ssum, o, 32);
        if (lane < 25) {
            float bt = e / ssum;
            sBeta[lane] = bt;
            out[FEA_SZ + (size_t)b * 260 + s * 26 + 1 + lane] = bt;
        }
    }
    __syncthreads();

    if (tid < 128) {
        float acc = 0.f;
        #pragma unroll
        for (int t = 0; t < 25; ++t) acc += sBeta[t] * sNbr[t][tid];
        aggF[((size_t)b * 10 + s) * 128 + tid] = acc;
    }
}

// Fused head: 2 b's per block, grid 1024, 4 blocks/CU.
// Wave w: bw = w>>1 (which b), wv = w&1 (0: x-part*W1V, 1: agg-part*W2V).
// Lane: kq2 = lane>>5 (64-k sub-chunk), cg = lane&31, c0 = cg*4 (4 cols).
__global__ __launch_bounds__(256, 4) void hopfused_kernel(
    const float* __restrict__ x, const int* __restrict__ samples,
    const float* __restrict__ ws, float* __restrict__ out)
{
    const int b0 = blockIdx.x * 2;
    const int tid = threadIdx.x;
    const int w = tid >> 6;
    const int bw = w >> 1, wv = w & 1;
    const int lane = tid & 63;
    const int kq2 = lane >> 5, cg = lane & 31;
    const int c0 = cg * 4;
    const int rb = bw * 11;

    __shared__ __align__(16) float sX[44][128];      // 0..21: x rows, 22..43: agg rows
    __shared__ __align__(16) float4 sPart[2][32][11];
    __shared__ __align__(16) float sHopH[2][128];
    __shared__ float sD[22];
    __shared__ float sBeta0[2][10];
    __shared__ int sNode[22];

    if (tid < 22) {
        int bb = tid / 11, s = tid - bb * 11;
        sNode[tid] = (s < 10) ? samples[(size_t)(b0 + bb) * NSAMP + 1 + s]
                              : samples[(size_t)(b0 + bb) * NSAMP];
    }
    __syncthreads();

    // stage x rows (0..21) and aggF rows (22..43, s<10 only) in one pass
    for (int i = tid; i < 42 * 32; i += 256) {
        int row = i >> 5, seg = i & 31;
        float4 v;
        if (row < 22) {
            v = *(const float4*)(x + (size_t)sNode[row] * DC + seg * 4);
            *(float4*)(&sX[row][seg * 4]) = v;
        } else {
            int idx = row - 22, bb = idx / 10, s = idx - bb * 10;
            v = *(const float4*)(ws + WS_AGGF + ((size_t)(b0 + bb) * 10 + s) * DC + seg * 4);
            *(float4*)(&sX[22 + bb * 11 + s][seg * 4]) = v;
        }
    }
    __syncthreads();

    // att dots: s<10 -> t1.a2 ; s==10 -> t0.a1
    {
        int g = tid >> 5, ln = tid & 31;
        for (int rd = 0, r = g; rd < 3; ++rd, r += 8) {
            float p = 0.f;
            if (r < 22) {
                int s = (r < 11) ? r : r - 11;
                const float* av = ws + ((s < 10) ? 128 : 0);
                float4 v = *(const float4*)(&sX[r][ln * 4]);
                float4 a = *(const float4*)(av + ln * 4);
                p = dot4(v, a);
            }
            for (int o = 16; o > 0; o >>= 1) p += __shfl_xor(p, o, 32);
            if (r < 22 && ln == 0) sD[r] = p;
        }
    }
    __syncthreads();

    // beta0 per bb
    if (tid < 32) {
        int bb = tid >> 4, j = tid & 15;
        float cc = sD[bb * 11 + 10];
        float v = (j < 10) ? lrelu(cc + sD[bb * 11 + j]) : -3.4e38f;
        float m = v;
        for (int o = 8; o > 0; o >>= 1) m = fmaxf(m, __shfl_xor(m, o, 16));
        float e = (j < 10) ? __expf(v - m) : 0.f;
        float ss = e;
        for (int o = 8; o > 0; o >>= 1) ss += __shfl_xor(ss, o, 16);
        if (j < 10) sBeta0[bb][j] = e / ss;
    }
    __syncthreads();

    // tbar -> agg row s==10:  sX[22 + bb*11 + 10][n]
    {
        int bb = tid >> 7, n = tid & 127;
        float acc = 0.f;
        #pragma unroll
        for (int s = 0; s < 10; ++s) acc += sBeta0[bb][s] * sX[bb * 11 + s][n];
        sX[22 + bb * 11 + 10][n] = acc;
    }
    __syncthreads();

    // ---- GEMM: this wave covers 64 k's (kq2 half of its 128-k part) x 4 cols ----
    const float* wb = ws + WS_WVT + (size_t)(wv ? 128 : 0) * 128;
    const int arow = (wv ? 22 + rb : rb);
    float4 acc[11];
    #pragma unroll
    for (int s = 0; s < 11; ++s) acc[s] = make_float4(0.f, 0.f, 0.f, 0.f);

    #pragma unroll 2
    for (int kk = 0; kk < 16; ++kk) {
        const int k = (kq2 << 6) + (kk << 2);
        const float* wp = wb + (size_t)k * 128 + c0;
        float4 w0 = *(const float4*)(wp);
        float4 w1 = *(const float4*)(wp + 128);
        float4 w2 = *(const float4*)(wp + 256);
        float4 w3 = *(const float4*)(wp + 384);
        #pragma unroll
        for (int s = 0; s < 11; ++s) {
            float4 a = *(const float4*)(&sX[arow + s][k]);
            acc[s].x += a.x * w0.x + a.y * w1.x + a.z * w2.x + a.w * w3.x;
            acc[s].y += a.x * w0.y + a.y * w1.y + a.z * w2.y + a.w * w3.y;
            acc[s].z += a.x * w0.z + a.y * w1.z + a.z * w2.z + a.w * w3.z;
            acc[s].w += a.x * w0.w + a.y * w1.w + a.z * w2.w + a.w * w3.w;
        }
    }

    // combine kq2 halves within wave
    #pragma unroll
    for (int s = 0; s < 11; ++s) {
        acc[s].x += __shfl_xor(acc[s].x, 32, 64);
        acc[s].y += __shfl_xor(acc[s].y, 32, 64);
        acc[s].z += __shfl_xor(acc[s].z, 32, 64);
        acc[s].w += __shfl_xor(acc[s].w, 32, 64);
    }

    // cross-wave combine: wv==1 writes partials, wv==0 adds
    if (wv == 1 && lane < 32) {
        #pragma unroll
        for (int s = 0; s < 11; ++s) sPart[bw][cg][s] = acc[s];
    }
    __syncthreads();

    if (wv == 0 && lane < 32) {
        float h[11][4];
        #pragma unroll
        for (int s = 0; s < 11; ++s) {
            float4 p = sPart[bw][cg][s];
            h[s][0] = sigm(acc[s].x + p.x);
            h[s][1] = sigm(acc[s].y + p.y);
            h[s][2] = sigm(acc[s].z + p.z);
            h[s][3] = sigm(acc[s].w + p.w);
        }

        // logits (butterfly gives all 32 lanes the sum)
        const float* b1v = ws + 256;
        const float* b2v = ws + 384;
        float lg[11];
        #pragma unroll
        for (int s = 0; s < 11; ++s) {
            const float* vb = (s < 10) ? b2v : b1v;
            float p = h[s][0] * vb[c0] + h[s][1] * vb[c0 + 1]
                    + h[s][2] * vb[c0 + 2] + h[s][3] * vb[c0 + 3];
            #pragma unroll
            for (int o = 16; o > 0; o >>= 1) p += __shfl_xor(p, o, 32);
            lg[s] = p;
        }

        // beta_h softmax (replicated per lane)
        float bh[10];
        float mm = -3.4e38f;
        float lv[10];
        #pragma unroll
        for (int s = 0; s < 10; ++s) {
            lv[s] = lrelu(lg[10] + lg[s]);
            mm = fmaxf(mm, lv[s]);
        }
        float ssum = 0.f;
        #pragma unroll
        for (int s = 0; s < 10; ++s) { bh[s] = __expf(lv[s] - mm); ssum += bh[s]; }
        float inv = 1.f / ssum;
        #pragma unroll
        for (int s = 0; s < 10; ++s) bh[s] *= inv;

        if (lane < 10)
            out[FEA_SZ + (size_t)(b0 + bw) * 260 + lane * 26] = bh[lane];

        // hopH cols
        float4 hh = make_float4(0.f, 0.f, 0.f, 0.f);
        #pragma unroll
        for (int s = 0; s < 10; ++s) {
            hh.x += bh[s] * h[s][0];
            hh.y += bh[s] * h[s][1];
            hh.z += bh[s] * h[s][2];
            hh.w += bh[s] * h[s][3];
        }
        *(float4*)(&sHopH[bw][c0]) = hh;
    }
    __syncthreads();

    // final projection: fea_out[c] = sum_dd hopH[dd] * V0t[dd][c]; out is fea_out^T
    {
        const float* v0t = ws + WS_V0T;
        int c = tid & 127, bb = tid >> 7;
        float acc2 = 0.f;
        for (int dd = 0; dd < 128; dd += 4) {
            float4 hh = *(const float4*)(&sHopH[bb][dd]);
            acc2 += hh.x * v0t[(size_t)(dd + 0) * 128 + c]
                  + hh.y * v0t[(size_t)(dd + 1) * 128 + c]
                  + hh.z * v0t[(size_t)(dd + 2) * 128 + c]
                  + hh.w * v0t[(size_t)(dd + 3) * 128 + c];
        }
        out[(size_t)c * 2048 + b0 + bb] = acc2;
    }
}

extern "C" void kernel_launch(void* const* d_in, const int* in_sizes, int n_in,
                              void* d_out, int out_size, void* d_ws, size_t ws_size,
                              hipStream_t stream) {
    const float* x      = (const float*)d_in[0];
    const int*   samples= (const int*)d_in[1];
    const float* V1h1a  = (const float*)d_in[2];
    const float* w1h1   = (const float*)d_in[3];
    const float* V1h0a  = (const float*)d_in[4];
    const float* w1h0   = (const float*)d_in[5];
    const float* V1h1   = (const float*)d_in[6];
    const float* V1h0   = (const float*)d_in[7];
    const float* Whops  = (const float*)d_in[8];
    float* outp = (float*)d_out;
    float* ws   = (float*)d_ws;

    hipLaunchKernelGGL(prep_all_kernel, dim3(193), dim3(256), 0, stream,
                       V1h1a, w1h1, V1h0a, w1h0, V1h1, Whops, V1h0, ws);
    hipLaunchKernelGGL(nbr_kernel, dim3(10, 2048), dim3(256), 0, stream,
                       x, samples, ws, ws + WS_AGGF, outp);
    hipLaunchKernelGGL(hopfused_kernel, dim3(1024), dim3(256), 0, stream,
                       x, samples, ws, outp);
}

// Round 8
// 71.786 us; speedup vs baseline: 3.4977x; 1.3033x over previous
//
#include <hip/hip_runtime.h>
#include <math.h>

#define S1C 10
#define S2C 25
#define DC 128
#define NSAMP 261
#define NBATCH 2048
#define FEA_SZ (128*2048)

// ws layout (floats):
//   [0:128)    a1 = V1h1a^T w1[:128]
//   [128:256)  a2 = V1h1a^T w1[128:]
//   [256:384)  b1 = V1h0a^T w0[:128]
//   [384:512)  b2 = V1h0a^T w0[128:]
//   WS_BPK:  Bpack bf16 (32768 ushorts = 16384 float slots):
//            element ((nt*8+kb)*64 + lane)*8 + j  =  bf16( Wcat[d][k] )
//            d = nt*16 + (lane&15), k = kb*32 + ((lane>>4)&3)*8 + j
//            Wcat[d][k] = k<128 ? W1V[d][k] : W2V[d][k-128]
//   WS_V0T:  V0t[dd][l] = V1h0[l][dd]  (f32)
//   WS_AGGF: aggF[b][s][128] bf16 (ushort)
#define WS_BPK   512
#define WS_V0T   (WS_BPK + 16384)
#define WS_AGGF  (WS_V0T + 16384)

typedef float f32x4 __attribute__((ext_vector_type(4)));
typedef short s16x8 __attribute__((ext_vector_type(8)));

__device__ __forceinline__ float lrelu(float v) { return v > 0.f ? v : 0.01f * v; }
__device__ __forceinline__ float sigm(float v) { return 1.f / (1.f + __expf(-v)); }
__device__ __forceinline__ float dot4(float4 a, float4 b) {
    return a.x * b.x + a.y * b.y + a.z * b.z + a.w * b.w;
}
__device__ __forceinline__ unsigned short f2bf(float f) {
    unsigned u = __float_as_uint(f);
    unsigned r = (u + 0x7FFFu + ((u >> 16) & 1u)) >> 16;
    return (unsigned short)r;
}

// Merged prep: blk 0 -> a1/a2/b1/b2; blks 1..128 -> Bpack; blks 129..192 -> V0t
__global__ void prep_all_kernel(const float* __restrict__ Vh1a, const float* __restrict__ w1,
                                const float* __restrict__ Vh0a, const float* __restrict__ w0,
                                const float* __restrict__ V1h1, const float* __restrict__ Whops,
                                const float* __restrict__ V1h0, float* __restrict__ ws) {
    const int blk = blockIdx.x, tid = threadIdx.x;
    if (blk == 0) {
        for (int o = tid; o < 512; o += 256) {
            int which = o >> 7, n = o & 127;
            const float* V = (which < 2) ? Vh1a : Vh0a;
            const float* w = (which < 2) ? w1 : w0;
            int off = (which & 1) * 128;
            float acc = 0.f;
            for (int l = 0; l < 128; ++l) acc += V[l * 128 + n] * w[off + l];
            ws[o] = acc;
        }
    } else if (blk <= 128) {
        int e = (blk - 1) * 256 + tid;          // 0..32767
        int j  = e & 7;
        int l  = (e >> 3) & 63;
        int kb = (e >> 9) & 7;
        int nt = (e >> 12) & 7;
        int d  = nt * 16 + (l & 15);
        int k  = kb * 32 + ((l >> 4) & 3) * 8 + j;
        int which = k >> 7, kk = k & 127;
        float acc = 0.f;
        for (int jj = 0; jj < 128; ++jj)
            acc += Whops[(size_t)d * 256 + which * 128 + jj] * V1h1[(size_t)jj * 128 + kk];
        unsigned short* bpk = (unsigned short*)(ws + WS_BPK);
        bpk[e] = f2bf(acc);
    } else {
        int dd = (blk - 129) * 2 + (tid >> 7);
        int l = tid & 127;
        ws[WS_V0T + (size_t)dd * 128 + l] = V1h0[(size_t)l * 128 + dd];
    }
}

// One block per (b,s): grid = dim3(10, 2048). beta1 + aggF (bf16).
__global__ __launch_bounds__(256) void nbr_kernel(
    const float* __restrict__ x, const int* __restrict__ samples,
    const float* __restrict__ ws, unsigned short* __restrict__ aggF,
    float* __restrict__ out)
{
    const int s = blockIdx.x, b = blockIdx.y;
    const int tid = threadIdx.x, g = tid >> 5, lane = tid & 31;

    __shared__ __align__(16) float sNbr[25][132];
    __shared__ float sD[26];
    __shared__ float sBeta[25];

    float4 a1v = *(const float4*)(ws + lane * 4);
    float4 a2v = *(const float4*)(ws + 128 + lane * 4);
    const int* sidx = samples + (size_t)b * NSAMP;

    const bool has3 = (g < 2);
    int n0 = sidx[11 + s * S2C + g];
    int n1 = sidx[11 + s * S2C + 8 + g];
    int n2 = sidx[11 + s * S2C + 16 + g];
    int n3 = has3 ? ((g == 0) ? sidx[11 + s * S2C + 24] : sidx[1 + s]) : 0;

    float4 v0 = *(const float4*)(x + (size_t)n0 * DC + lane * 4);
    float4 v1 = *(const float4*)(x + (size_t)n1 * DC + lane * 4);
    float4 v2 = *(const float4*)(x + (size_t)n2 * DC + lane * 4);
    float4 v3 = make_float4(0.f, 0.f, 0.f, 0.f);
    if (has3) v3 = *(const float4*)(x + (size_t)n3 * DC + lane * 4);

    *(float4*)(&sNbr[g][lane * 4]) = v0;
    *(float4*)(&sNbr[8 + g][lane * 4]) = v1;
    *(float4*)(&sNbr[16 + g][lane * 4]) = v2;
    if (g == 0) *(float4*)(&sNbr[24][lane * 4]) = v3;

    float p0 = dot4(v0, a2v);
    float p1 = dot4(v1, a2v);
    float p2 = dot4(v2, a2v);
    float p3 = has3 ? dot4(v3, (g == 0) ? a2v : a1v) : 0.f;
    #pragma unroll
    for (int o = 16; o > 0; o >>= 1) {
        p0 += __shfl_xor(p0, o, 32);
        p1 += __shfl_xor(p1, o, 32);
        p2 += __shfl_xor(p2, o, 32);
        p3 += __shfl_xor(p3, o, 32);
    }
    if (lane == 0) {
        sD[g] = p0; sD[8 + g] = p1; sD[16 + g] = p2;
        if (has3) sD[24 + g] = p3;
    }
    __syncthreads();

    if (tid < 32) {
        float c1 = sD[25];
        float v = (lane < 25) ? lrelu(c1 + sD[lane]) : -3.4e38f;
        float m = v;
        for (int o = 16; o > 0; o >>= 1) m = fmaxf(m, __shfl_xor(m, o, 32));
        float e = (lane < 25) ? __expf(v - m) : 0.f;
        float ssum = e;
        for (int o = 16; o > 0; o >>= 1) ssum += __shfl_xor(ssum, o, 32);
        if (lane < 25) {
            float bt = e / ssum;
            sBeta[lane] = bt;
            out[FEA_SZ + (size_t)b * 260 + s * 26 + 1 + lane] = bt;
        }
    }
    __syncthreads();

    if (tid < 128) {
        float acc = 0.f;
        #pragma unroll
        for (int t = 0; t < 25; ++t) acc += sBeta[t] * sNbr[t][tid];
        aggF[((size_t)b * 10 + s) * 128 + tid] = f2bf(acc);
    }
}

// Fused head with MFMA GEMM. 2 b's per block, grid 1024.
// GEMM: M=32 (rows: b0 s0..10 at 0..10, b1 s0..10 at 16..26, rest pad),
//       N=128 (hop dims), K=256 ([x-row ; agg-row]).
// Wave w handles n-tiles {2w, 2w+1}; acc = 2 m-tiles x 2 n-tiles.
__global__ __launch_bounds__(256, 4) void hopfused_kernel(
    const float* __restrict__ x, const int* __restrict__ samples,
    const float* __restrict__ ws, const unsigned short* __restrict__ aggF,
    float* __restrict__ out)
{
    const int b0 = blockIdx.x * 2;
    const int tid = threadIdx.x;
    const int w = tid >> 6;
    const int lane = tid & 63;
    const int lg16 = lane >> 4;
    const int l15 = lane & 15;

    __shared__ __align__(16) float sX[22][128];
    __shared__ __align__(16) short sXb[32][264];   // bf16 act rows, padded stride
    __shared__ float sLgP[4][32];
    __shared__ __align__(16) float sHopH[2][128];
    __shared__ float sD[22];
    __shared__ float sBeta0[2][10];
    __shared__ float sBH[2][10];
    __shared__ int sNode[22];

    if (tid < 22) {
        int bb = tid / 11, s = tid - bb * 11;
        sNode[tid] = (s < 10) ? samples[(size_t)(b0 + bb) * NSAMP + 1 + s]
                              : samples[(size_t)(b0 + bb) * NSAMP];
    }
    // zero pad rows 11..15, 27..31
    for (int i = tid; i < 330; i += 256) {
        int rr = i / 33, c8 = i - rr * 33;
        int row = (rr < 5) ? 11 + rr : 22 + rr;
        s16x8 z = (s16x8)(short)0;
        *(s16x8*)(&sXb[row][c8 * 8]) = z;
    }
    __syncthreads();

    // gather 22 x-rows (f32) + 20 aggF rows (bf16, k>=128 half)
    for (int i = tid; i < 22 * 32; i += 256) {
        int row = i >> 5, seg = i & 31;
        *(float4*)(&sX[row][seg * 4]) =
            *(const float4*)(x + (size_t)sNode[row] * DC + seg * 4);
    }
    for (int i = tid; i < 320; i += 256) {
        int row20 = i >> 4, seg = i & 15;
        int bb = row20 / 10, s = row20 - bb * 10;
        *(s16x8*)(&sXb[bb * 16 + s][128 + seg * 8]) =
            *(const s16x8*)(aggF + ((size_t)(b0 + bb) * 10 + s) * 128 + seg * 8);
    }
    __syncthreads();

    // att dots: s<10 -> t1.a2 ; s==10 -> t0.a1
    {
        int gg = tid >> 5, ln = tid & 31;
        for (int rd = 0, r = gg; rd < 3; ++rd, r += 8) {
            float p = 0.f;
            if (r < 22) {
                int s = (r < 11) ? r : r - 11;
                const float* av = ws + ((s < 10) ? 128 : 0);
                float4 v = *(const float4*)(&sX[r][ln * 4]);
                float4 a = *(const float4*)(av + ln * 4);
                p = dot4(v, a);
            }
            for (int o = 16; o > 0; o >>= 1) p += __shfl_xor(p, o, 32);
            if (r < 22 && ln == 0) sD[r] = p;
        }
    }
    __syncthreads();

    // beta0 per bb
    if (tid < 32) {
        int bb = tid >> 4, j = tid & 15;
        float cc = sD[bb * 11 + 10];
        float v = (j < 10) ? lrelu(cc + sD[bb * 11 + j]) : -3.4e38f;
        float m = v;
        for (int o = 8; o > 0; o >>= 1) m = fmaxf(m, __shfl_xor(m, o, 16));
        float e = (j < 10) ? __expf(v - m) : 0.f;
        float ss = e;
        for (int o = 8; o > 0; o >>= 1) ss += __shfl_xor(ss, o, 16);
        if (j < 10) sBeta0[bb][j] = e / ss;
    }
    __syncthreads();

    // tbar -> bf16 row (k>=128 of row bb*16+10); convert x rows -> bf16 (k<128)
    {
        int bb = tid >> 7, n = tid & 127;
        float acc = 0.f;
        #pragma unroll
        for (int s = 0; s < 10; ++s) acc += sBeta0[bb][s] * sX[bb * 11 + s][n];
        sXb[bb * 16 + 10][128 + n] = (short)f2bf(acc);
    }
    for (int i = tid; i < 22 * 128; i += 256) {
        int m = i >> 7, k = i & 127;
        int row = (m < 11) ? m : m + 5;
        sXb[row][k] = (short)f2bf(sX[m][k]);
    }
    __syncthreads();

    // ---- MFMA GEMM ----
    const unsigned short* bpk = (const unsigned short*)(ws + WS_BPK);
    const int nt0 = 2 * w, nt1 = nt0 + 1;
    f32x4 acc00 = {0.f, 0.f, 0.f, 0.f}, acc01 = {0.f, 0.f, 0.f, 0.f};
    f32x4 acc10 = {0.f, 0.f, 0.f, 0.f}, acc11 = {0.f, 0.f, 0.f, 0.f};
    #pragma unroll
    for (int kb = 0; kb < 8; ++kb) {
        s16x8 a0 = *(const s16x8*)(&sXb[l15][kb * 32 + lg16 * 8]);
        s16x8 a1 = *(const s16x8*)(&sXb[16 + l15][kb * 32 + lg16 * 8]);
        s16x8 bw0 = *(const s16x8*)(bpk + ((size_t)(nt0 * 8 + kb) * 64 + lane) * 8);
        s16x8 bw1 = *(const s16x8*)(bpk + ((size_t)(nt1 * 8 + kb) * 64 + lane) * 8);
        acc00 = __builtin_amdgcn_mfma_f32_16x16x32_bf16(a0, bw0, acc00, 0, 0, 0);
        acc01 = __builtin_amdgcn_mfma_f32_16x16x32_bf16(a0, bw1, acc01, 0, 0, 0);
        acc10 = __builtin_amdgcn_mfma_f32_16x16x32_bf16(a1, bw0, acc10, 0, 0, 0);
        acc11 = __builtin_amdgcn_mfma_f32_16x16x32_bf16(a1, bw1, acc11, 0, 0, 0);
    }

    // sigmoid -> h fragments (D layout: col = lane&15 (+nt*16), row = lg16*4 + r (+mt*16))
    float h00[4], h01[4], h10[4], h11[4];
    #pragma unroll
    for (int r = 0; r < 4; ++r) {
        h00[r] = sigm(acc00[r]); h01[r] = sigm(acc01[r]);
        h10[r] = sigm(acc10[r]); h11[r] = sigm(acc11[r]);
    }

    // partial logits per row over this wave's 32 cols
    const int c0 = nt0 * 16 + l15, c1 = nt1 * 16 + l15;
    const float b1c0 = ws[256 + c0], b1c1 = ws[256 + c1];
    const float b2c0 = ws[384 + c0], b2c1 = ws[384 + c1];
    #pragma unroll
    for (int mt = 0; mt < 2; ++mt) {
        #pragma unroll
        for (int r = 0; r < 4; ++r) {
            int s = lg16 * 4 + r;
            float ha = mt ? h10[r] : h00[r];
            float hb = mt ? h11[r] : h01[r];
            float p;
            if (s < 10)       p = ha * b2c0 + hb * b2c1;
            else if (s == 10) p = ha * b1c0 + hb * b1c1;
            else              p = 0.f;
            #pragma unroll
            for (int o = 1; o < 16; o <<= 1) p += __shfl_xor(p, o, 64);
            if (l15 == 0) sLgP[w][mt * 16 + s] = p;
        }
    }
    __syncthreads();

    // beta_h per bb (combine 4 wave partials)
    if (tid < 32) {
        int bb = tid >> 4, j = tid & 15;
        float lgj = 0.f, lg10 = 0.f;
        #pragma unroll
        for (int wv = 0; wv < 4; ++wv) {
            lgj  += sLgP[wv][bb * 16 + j];
            lg10 += sLgP[wv][bb * 16 + 10];
        }
        float v = (j < 10) ? lrelu(lg10 + lgj) : -3.4e38f;
        float m = v;
        for (int o = 8; o > 0; o >>= 1) m = fmaxf(m, __shfl_xor(m, o, 16));
        float e = (j < 10) ? __expf(v - m) : 0.f;
        float ss = e;
        for (int o = 8; o > 0; o >>= 1) ss += __shfl_xor(ss, o, 16);
        if (j < 10) {
            float bh = e / ss;
            sBH[bb][j] = bh;
            out[FEA_SZ + (size_t)(b0 + bb) * 260 + j * 26] = bh;
        }
    }
    __syncthreads();

    // hopH[bb][c] = sum_s bh[s] * h[s][c]  (reduce over lane-groups)
    #pragma unroll
    for (int bb = 0; bb < 2; ++bb) {
        float p0 = 0.f, p1 = 0.f;
        #pragma unroll
        for (int r = 0; r < 4; ++r) {
            int s = lg16 * 4 + r;
            if (s < 10) {
                float bh = sBH[bb][s];
                p0 += bh * (bb ? h10[r] : h00[r]);
                p1 += bh * (bb ? h11[r] : h01[r]);
            }
        }
        p0 += __shfl_xor(p0, 16, 64); p0 += __shfl_xor(p0, 32, 64);
        p1 += __shfl_xor(p1, 16, 64); p1 += __shfl_xor(p1, 32, 64);
        if (lg16 == 0) {
            sHopH[bb][nt0 * 16 + l15] = p0;
            sHopH[bb][nt1 * 16 + l15] = p1;
        }
    }
    __syncthreads();

    // final projection: fea_out[c] = sum_dd hopH[dd] * V0t[dd][c]; out is fea_out^T
    {
        const float* v0t = ws + WS_V0T;
        int c = tid & 127, bb = tid >> 7;
        float acc2 = 0.f;
        for (int dd = 0; dd < 128; dd += 4) {
            float4 hh = *(const float4*)(&sHopH[bb][dd]);
            acc2 += hh.x * v0t[(size_t)(dd + 0) * 128 + c]
                  + hh.y * v0t[(size_t)(dd + 1) * 128 + c]
                  + hh.z * v0t[(size_t)(dd + 2) * 128 + c]
                  + hh.w * v0t[(size_t)(dd + 3) * 128 + c];
        }
        out[(size_t)c * 2048 + b0 + bb] = acc2;
    }
}

extern "C" void kernel_launch(void* const* d_in, const int* in_sizes, int n_in,
                              void* d_out, int out_size, void* d_ws, size_t ws_size,
                              hipStream_t stream) {
    const float* x      = (const float*)d_in[0];
    const int*   samples= (const int*)d_in[1];
    const float* V1h1a  = (const float*)d_in[2];
    const float* w1h1   = (const float*)d_in[3];
    const float* V1h0a  = (const float*)d_in[4];
    const float* w1h0   = (const float*)d_in[5];
    const float* V1h1   = (const float*)d_in[6];
    const float* V1h0   = (const float*)d_in[7];
    const float* Whops  = (const float*)d_in[8];
    float* outp = (float*)d_out;
    float* ws   = (float*)d_ws;
    unsigned short* aggF = (unsigned short*)(ws + WS_AGGF);

    hipLaunchKernelGGL(prep_all_kernel, dim3(193), dim3(256), 0, stream,
                       V1h1a, w1h1, V1h0a, w1h0, V1h1, Whops, V1h0, ws);
    hipLaunchKernelGGL(nbr_kernel, dim3(10, 2048), dim3(256), 0, stream,
                       x, samples, ws, aggF, outp);
    hipLaunchKernelGGL(hopfused_kernel, dim3(1024), dim3(256), 0, stream,
                       x, samples, ws, aggF, outp);
}